// Round 10
// baseline (2493.230 us; speedup 1.0000x reference)
//
#include <hip/hip_runtime.h>
#include <hip/hip_bf16.h>
#include <stdint.h>

// Problem constants
#define N_B   32
#define N_W   128
#define N_BW  4096
#define N_Q   256
#define N_H   512
#define N_A   128
#define N_C   16
#define N_G   2048   // 4*H

using bf16x8 = __attribute__((ext_vector_type(8))) __bf16;
using f32x4  = __attribute__((ext_vector_type(4))) float;

__device__ __forceinline__ unsigned short f2bf(float x) {
    union { float f; uint32_t u; } v; v.f = x;
    return (unsigned short)((v.u + 0x7FFFu + ((v.u >> 16) & 1u)) >> 16);
}

// workspace offsets (bytes)
#define WS_WHH   0                                  // 2048*512*2 = 2097152
#define WS_WO    2097152                            // 128*512*2  = 131072
#define WS_WP    (2097152 + 131072)                 // 512*256*2  = 262144
#define WS_WIHT  (2097152 + 131072 + 262144)        // 128*2048*4 = 1048576 (bias folded in)

__global__ void prep_kernel(const float* __restrict__ Whh, const float* __restrict__ Wo,
                            const float* __restrict__ Wp,  const float* __restrict__ bih,
                            const float* __restrict__ bhh, const float* __restrict__ Wih,
                            unsigned short* __restrict__ whh_bf, unsigned short* __restrict__ wo_bf,
                            unsigned short* __restrict__ wp_bf, float* __restrict__ wih_tb)
{
    const int NWHH = N_G * N_H;   // 1048576
    const int NWO  = N_A * N_H;   // 65536
    const int NWP  = N_H * N_Q;   // 131072
    const int NWT  = N_A * N_G;   // 262144
    const int total = NWHH + NWO + NWP + NWT;
    for (int i = blockIdx.x * blockDim.x + threadIdx.x; i < total; i += gridDim.x * blockDim.x) {
        if (i < NWHH) { whh_bf[i] = f2bf(Whh[i]); }
        else if (i < NWHH + NWO) { int j = i - NWHH; wo_bf[j] = f2bf(Wo[j]); }
        else if (i < NWHH + NWO + NWP) { int j = i - NWHH - NWO; wp_bf[j] = f2bf(Wp[j]); }
        else { int j = i - NWHH - NWO - NWP; int c = j >> 11; int n = j & (N_G - 1);
               // transposed W_ih with bias folded: wih_tb[c][n] = W_ih[n][c] + b_ih[n] + b_hh[n]
               wih_tb[j] = Wih[n * N_A + c] + bih[n] + bhh[n]; }
    }
}

// One workgroup = 16 sequences, full 16-step recurrence. 8 waves; wave w owns
// h-columns [64w, 64w+64) across all 4 gate quadrants (i,f,g,o in-register).
// B (W_hh / Wo) is streamed with an explicit 2-deep 8-fragment double-buffer
// pipeline that rolls across all 17 tiles of a step and across steps.
//
// VGPR history: __launch_bounds__(512,2) AND (512) both compiled to 128 VGPRs
// (backend default budgets 4 waves/SIMD for an 8-wave WG) -> the b0/b1 ring
// spilled to scratch (~494 MB/dispatch excess WRITE_SIZE, rounds 5-6).
// launch_bounds' min-waves arg only bounds occupancy from BELOW; the
// amdgpu_waves_per_eu MAX arg (=2) is what bounds it from ABOVE and lifts the
// register budget to 256. Grid is 256 blocks = 1 block/CU = 2 waves/SIMD, so
// real occupancy is unchanged.
__global__ __launch_bounds__(512) __attribute__((amdgpu_waves_per_eu(1, 2)))
void lstm_kernel(
    const float* __restrict__ qr, const int* __restrict__ tch,
    const float* __restrict__ bp, const unsigned short* __restrict__ whh_bf,
    const unsigned short* __restrict__ wo_bf, const unsigned short* __restrict__ wp_bf,
    const float* __restrict__ wih_tb, const float* __restrict__ bo,
    float* __restrict__ out)
{
    __shared__ unsigned short h_lds[16][520];   // h state, bf16, padded (8-way balanced b128 reads)
    __shared__ unsigned short qr_bf[16][264];   // staged quantized_repr rows, bf16
    __shared__ float logits_lds[16][128];       // per-step logits staging for coalesced stores
    __shared__ int char_lds[N_C][16];           // input char per (step, row)

    const int tid  = threadIdx.x;
    const int wid  = tid >> 6;
    const int lane = tid & 63;
    const int l15  = lane & 15;
    const int l4   = lane >> 4;
    const int r0   = blockIdx.x << 4;

    // stage qr rows (bf16) — coalesced
    for (int idx = tid; idx < 16 * N_Q; idx += 512) {
        int r = idx >> 8, k = idx & (N_Q - 1);
        qr_bf[r][k] = f2bf(qr[(r0 + r) * N_Q + k]);
    }
    // teacher-forcing chars: step 0 = start token (index 0), step t = tc[r][t-1]
    if (tid < N_C * 16) {
        int t = tid >> 4, r = tid & 15;
        int c = 0;
        if (t > 0) {
            c = tch[(r0 + r) * N_C + (t - 1)];
            if (c < 0 || c >= N_A) c = 0;
        }
        char_lds[t][r] = c;
    }
    __syncthreads();

    // ---- h0 = qr @ Wp.T + bp (MFMA, per-wave 4 column tiles) ----
    for (int cg = 0; cg < 4; cg++) {
        const int j0 = (wid * 4 + cg) * 16;
        const float bpv = bp[j0 + l15];
        f32x4 acc = {bpv, bpv, bpv, bpv};
        const unsigned short* bptr = wp_bf + (j0 + l15) * N_Q + l4 * 8;
        #pragma unroll
        for (int kk = 0; kk < N_Q / 32; kk++) {
            bf16x8 afr = *reinterpret_cast<const bf16x8*>(&qr_bf[l15][kk * 32 + l4 * 8]);
            bf16x8 bfr = *reinterpret_cast<const bf16x8*>(bptr + kk * 32);
            acc = __builtin_amdgcn_mfma_f32_16x16x32_bf16(afr, bfr, acc, 0, 0, 0);
        }
        #pragma unroll
        for (int j = 0; j < 4; j++)
            h_lds[l4 * 4 + j][j0 + l15] = f2bf(acc[j]);
    }
    __syncthreads();

    const float bo_v = bo[wid * 16 + l15];

    f32x4 cst[4];
    #pragma unroll
    for (int cg = 0; cg < 4; cg++) cst[cg] = {0.f, 0.f, 0.f, 0.f};

    bf16x8 afrag[16];
    #pragma unroll
    for (int kk = 0; kk < 16; kk++)
        afrag[kk] = *reinterpret_cast<const bf16x8*>(&h_lds[l15][kk * 32 + l4 * 8]);

    // ---- prime the B pipeline: tile 0 (cg=0,q=0) halves 0 and 1 ----
    const unsigned short* pb_t0 = whh_bf + (size_t)(wid * 64 + l15) * N_H + l4 * 8;
    bf16x8 b0[8], b1[8];
    #pragma unroll
    for (int j = 0; j < 8; j++) b0[j] = *reinterpret_cast<const bf16x8*>(pb_t0 + j * 32);
    #pragma unroll
    for (int j = 0; j < 8; j++) b1[j] = *reinterpret_cast<const bf16x8*>(pb_t0 + 256 + j * 32);

    // chars + input-term prefetch for (t=0, tile 0)
    int ch[4];
    #pragma unroll
    for (int j = 0; j < 4; j++) ch[j] = char_lds[0][l4 * 4 + j];
    f32x4 inA, inB;
    #pragma unroll
    for (int j = 0; j < 4; j++)
        inA[j] = wih_tb[(size_t)ch[j] * N_G + (wid * 64 + l15)];

    for (int t = 0; t < N_C; t++) {
        f32x4 gacc[4];
        f32x4 hfrag;
        int chn[4];

        #pragma unroll
        for (int tile = 0; tile < 16; tile++) {
            const int cg = tile >> 2, q = tile & 3;

            // next tile's B base (tile 15 -> Wo for this step's logits)
            const unsigned short* nb;
            int ncol = 0;
            if (tile == 15) {
                nb = wo_bf + (size_t)(wid * 16 + l15) * N_H + l4 * 8;
            } else {
                const int nt = tile + 1, ncg = nt >> 2, nq = nt & 3;
                ncol = nq * N_H + wid * 64 + ncg * 16 + l15;
                nb = whh_bf + (size_t)ncol * N_H + l4 * 8;
            }

            // input-term prefetch for the next tile (consumed at next tile's end)
            if (tile == 15) {
                const int tn = (t + 1 < N_C) ? t + 1 : N_C - 1;
                #pragma unroll
                for (int j = 0; j < 4; j++) chn[j] = char_lds[tn][l4 * 4 + j];
                #pragma unroll
                for (int j = 0; j < 4; j++)
                    inA[j] = wih_tb[(size_t)chn[j] * N_G + (wid * 64 + l15)];
            } else {
                if (tile & 1) {
                    #pragma unroll
                    for (int j = 0; j < 4; j++)
                        inA[j] = wih_tb[(size_t)ch[j] * N_G + ncol];
                } else {
                    #pragma unroll
                    for (int j = 0; j < 4; j++)
                        inB[j] = wih_tb[(size_t)ch[j] * N_G + ncol];
                }
            }

            f32x4 acc = {0.f, 0.f, 0.f, 0.f};
            // consume half 0, then refill b0 with next tile's half 0
            #pragma unroll
            for (int j = 0; j < 8; j++)
                acc = __builtin_amdgcn_mfma_f32_16x16x32_bf16(afrag[j], b0[j], acc, 0, 0, 0);
            #pragma unroll
            for (int j = 0; j < 8; j++) b0[j] = *reinterpret_cast<const bf16x8*>(nb + j * 32);
            // consume half 1, then refill b1 with next tile's half 1
            #pragma unroll
            for (int j = 0; j < 8; j++)
                acc = __builtin_amdgcn_mfma_f32_16x16x32_bf16(afrag[8 + j], b1[j], acc, 0, 0, 0);
            #pragma unroll
            for (int j = 0; j < 8; j++) b1[j] = *reinterpret_cast<const bf16x8*>(nb + 256 + j * 32);

            // add prefetched input term (bias folded in)
            acc += (tile & 1) ? inB : inA;
            gacc[q] = acc;

            if (q == 3) {
                // LSTM elementwise — i,f,g,o resident in this wave's registers
                #pragma unroll
                for (int j = 0; j < 4; j++) {
                    const float iv = gacc[0][j], fv = gacc[1][j], gv = gacc[2][j], ov = gacc[3][j];
                    const float si = 1.f / (1.f + __expf(-iv));
                    const float sf = 1.f / (1.f + __expf(-fv));
                    const float so = 1.f / (1.f + __expf(-ov));
                    const float tg = 1.f - 2.f / (__expf(2.f * gv) + 1.f);
                    const float cn = sf * cst[cg][j] + si * tg;
                    cst[cg][j] = cn;
                    const float th = 1.f - 2.f / (__expf(2.f * cn) + 1.f);
                    hfrag[j] = so * th;
                }
                const int hc = wid * 64 + cg * 16 + l15;
                #pragma unroll
                for (int j = 0; j < 4; j++)
                    h_lds[l4 * 4 + j][hc] = f2bf(hfrag[j]);
            }
        }
        #pragma unroll
        for (int j = 0; j < 4; j++) ch[j] = chn[j];

        __syncthreads();   // new h complete in LDS

        // reload A-fragments (new h)
        #pragma unroll
        for (int kk = 0; kk < 16; kk++)
            afrag[kk] = *reinterpret_cast<const bf16x8*>(&h_lds[l15][kk * 32 + l4 * 8]);

        // logits = h_new @ Wo.T + bo ; b0/b1 hold Wo frags; refill with next
        // step's tile-0 W_hh frags as we consume them.
        f32x4 lacc = {bo_v, bo_v, bo_v, bo_v};
        #pragma unroll
        for (int j = 0; j < 8; j++)
            lacc = __builtin_amdgcn_mfma_f32_16x16x32_bf16(afrag[j], b0[j], lacc, 0, 0, 0);
        #pragma unroll
        for (int j = 0; j < 8; j++) b0[j] = *reinterpret_cast<const bf16x8*>(pb_t0 + j * 32);
        #pragma unroll
        for (int j = 0; j < 8; j++)
            lacc = __builtin_amdgcn_mfma_f32_16x16x32_bf16(afrag[8 + j], b1[j], lacc, 0, 0, 0);
        #pragma unroll
        for (int j = 0; j < 8; j++) b1[j] = *reinterpret_cast<const bf16x8*>(pb_t0 + 256 + j * 32);

        #pragma unroll
        for (int j = 0; j < 4; j++)
            logits_lds[l4 * 4 + j][wid * 16 + l15] = lacc[j];
        __syncthreads();

        // coalesced non-temporal store: 16 rows x 512B contiguous segments
        {
            const int row = tid >> 5, seg = tid & 31;
            f32x4 v = *reinterpret_cast<const f32x4*>(&logits_lds[row][seg * 4]);
            f32x4* dst = reinterpret_cast<f32x4*>(
                out + ((size_t)(r0 + row) * N_C + t) * N_A + seg * 4);
            __builtin_nontemporal_store(v, dst);
        }
    }
}

extern "C" void kernel_launch(void* const* d_in, const int* in_sizes, int n_in,
                              void* d_out, int out_size, void* d_ws, size_t ws_size,
                              hipStream_t stream) {
    const float* qr  = (const float*)d_in[0];
    const int*   tch = (const int*)d_in[1];
    const float* Wp  = (const float*)d_in[2];
    const float* bp  = (const float*)d_in[3];
    const float* Wih = (const float*)d_in[4];
    const float* Whh = (const float*)d_in[5];
    const float* bih = (const float*)d_in[6];
    const float* bhh = (const float*)d_in[7];
    const float* Wo  = (const float*)d_in[8];
    const float* bo  = (const float*)d_in[9];
    float* out = (float*)d_out;

    char* ws = (char*)d_ws;
    unsigned short* whh_bf = (unsigned short*)(ws + WS_WHH);
    unsigned short* wo_bf  = (unsigned short*)(ws + WS_WO);
    unsigned short* wp_bf  = (unsigned short*)(ws + WS_WP);
    float* wih_tb          = (float*)(ws + WS_WIHT);

    prep_kernel<<<1024, 256, 0, stream>>>(Whh, Wo, Wp, bih, bhh, Wih,
                                          whh_bf, wo_bf, wp_bf, wih_tb);
    lstm_kernel<<<N_BW / 16, 512, 0, stream>>>(qr, tch, bp, whh_bf, wo_bf, wp_bf,
                                               wih_tb, bo, out);
}

// Round 11
// 2404.661 us; speedup vs baseline: 1.0368x; 1.0368x over previous
//
#include <hip/hip_runtime.h>
#include <hip/hip_bf16.h>
#include <stdint.h>

// Problem constants
#define N_B   32
#define N_W   128
#define N_BW  4096
#define N_Q   256
#define N_H   512
#define N_A   128
#define N_C   16
#define N_G   2048   // 4*H

using bf16x8 = __attribute__((ext_vector_type(8))) __bf16;
using f32x4  = __attribute__((ext_vector_type(4))) float;

__device__ __forceinline__ unsigned short f2bf(float x) {
    union { float f; uint32_t u; } v; v.f = x;
    return (unsigned short)((v.u + 0x7FFFu + ((v.u >> 16) & 1u)) >> 16);
}

// workspace offsets (bytes)
#define WS_WHH   0                                  // 2048*512*2 = 2097152
#define WS_WO    2097152                            // 128*512*2  = 131072
#define WS_WP    (2097152 + 131072)                 // 512*256*2  = 262144
#define WS_WIHT  (2097152 + 131072 + 262144)        // 128*2048*4 = 1048576 (bias folded in)

__global__ void prep_kernel(const float* __restrict__ Whh, const float* __restrict__ Wo,
                            const float* __restrict__ Wp,  const float* __restrict__ bih,
                            const float* __restrict__ bhh, const float* __restrict__ Wih,
                            unsigned short* __restrict__ whh_bf, unsigned short* __restrict__ wo_bf,
                            unsigned short* __restrict__ wp_bf, float* __restrict__ wih_tb)
{
    const int NWHH = N_G * N_H;   // 1048576
    const int NWO  = N_A * N_H;   // 65536
    const int NWP  = N_H * N_Q;   // 131072
    const int NWT  = N_A * N_G;   // 262144
    const int total = NWHH + NWO + NWP + NWT;
    for (int i = blockIdx.x * blockDim.x + threadIdx.x; i < total; i += gridDim.x * blockDim.x) {
        if (i < NWHH) { whh_bf[i] = f2bf(Whh[i]); }
        else if (i < NWHH + NWO) { int j = i - NWHH; wo_bf[j] = f2bf(Wo[j]); }
        else if (i < NWHH + NWO + NWP) { int j = i - NWHH - NWO; wp_bf[j] = f2bf(Wp[j]); }
        else { int j = i - NWHH - NWO - NWP; int c = j >> 11; int n = j & (N_G - 1);
               // transposed W_ih with bias folded: wih_tb[c][n] = W_ih[n][c] + b_ih[n] + b_hh[n]
               wih_tb[j] = Wih[n * N_A + c] + bih[n] + bhh[n]; }
    }
}

// One workgroup = 16 sequences, 8 waves; wave w owns h-columns [64w,64w+64)
// across all 4 gate quadrants (i,f,g,o in-register).
//
// RESTRUCTURED FOR THE 128-VGPR BACKEND CAP (rounds 5/6/10: backend refuses
// >128 VGPRs for an 8-wave WG under launch_bounds(512,2)/(512)/waves_per_eu;
// the old 16-frag B-ring + persistent afrag[16] (~200 regs) spilled ~500 MB
// of scratch per dispatch). New dataflow (~100-110 regs, no spill):
//  - A-fragments: ds_read_b128 from LDS per use (no persistent snapshot);
//    h is DOUBLE-BUFFERED (read rd, write rd^1, flip at the per-step sync).
//  - B: 8-fragment round-robin ring, 8-slot lookahead: half A consumes frag
//    kk / refills slot kk with current tile's frag kk+8; half B consumes
//    kk+8 / refills with the NEXT tile's frag kk. Rolls across the 16 W_hh
//    tiles, the Wo (logits) tile, and into the next timestep.
//  - input one-hot term: single-slot prefetch (inN), loaded one tile ahead.
__global__ __launch_bounds__(512) __attribute__((amdgpu_waves_per_eu(1, 2)))
void lstm_kernel(
    const float* __restrict__ qr, const int* __restrict__ tch,
    const float* __restrict__ bp, const unsigned short* __restrict__ whh_bf,
    const unsigned short* __restrict__ wo_bf, const unsigned short* __restrict__ wp_bf,
    const float* __restrict__ wih_tb, const float* __restrict__ bo,
    float* __restrict__ out)
{
    __shared__ unsigned short h_lds[2][16][520]; // double-buffered h, bf16, padded
    __shared__ unsigned short qr_bf[16][264];    // staged quantized_repr rows, bf16
    __shared__ float logits_lds[16][128];        // per-step logits staging
    __shared__ int char_lds[N_C][16];            // input char per (step, row)

    const int tid  = threadIdx.x;
    const int wid  = tid >> 6;
    const int lane = tid & 63;
    const int l15  = lane & 15;
    const int l4   = lane >> 4;
    const int r0   = blockIdx.x << 4;

    // stage qr rows (bf16) — coalesced
    for (int idx = tid; idx < 16 * N_Q; idx += 512) {
        int r = idx >> 8, k = idx & (N_Q - 1);
        qr_bf[r][k] = f2bf(qr[(r0 + r) * N_Q + k]);
    }
    // teacher-forcing chars: step 0 = start token (index 0), step t = tc[r][t-1]
    if (tid < N_C * 16) {
        int t = tid >> 4, r = tid & 15;
        int c = 0;
        if (t > 0) {
            c = tch[(r0 + r) * N_C + (t - 1)];
            if (c < 0 || c >= N_A) c = 0;
        }
        char_lds[t][r] = c;
    }
    __syncthreads();

    // ---- h0 = qr @ Wp.T + bp (MFMA, per-wave 4 column tiles) -> h_lds[0] ----
    for (int cg = 0; cg < 4; cg++) {
        const int j0 = (wid * 4 + cg) * 16;
        const float bpv = bp[j0 + l15];
        f32x4 acc = {bpv, bpv, bpv, bpv};
        const unsigned short* bptr = wp_bf + (j0 + l15) * N_Q + l4 * 8;
        #pragma unroll
        for (int kk = 0; kk < N_Q / 32; kk++) {
            bf16x8 afr = *reinterpret_cast<const bf16x8*>(&qr_bf[l15][kk * 32 + l4 * 8]);
            bf16x8 bfr = *reinterpret_cast<const bf16x8*>(bptr + kk * 32);
            acc = __builtin_amdgcn_mfma_f32_16x16x32_bf16(afr, bfr, acc, 0, 0, 0);
        }
        #pragma unroll
        for (int j = 0; j < 4; j++)
            h_lds[0][l4 * 4 + j][j0 + l15] = f2bf(acc[j]);
    }
    __syncthreads();

    const float bo_v = bo[wid * 16 + l15];

    f32x4 cst[4];
    #pragma unroll
    for (int cg = 0; cg < 4; cg++) cst[cg] = {0.f, 0.f, 0.f, 0.f};

    // ---- prime the 8-frag B ring with tile 0 frags 0..7 ----
    const unsigned short* cb0 = whh_bf + (size_t)(wid * 64 + l15) * N_H + l4 * 8;
    bf16x8 b[8];
    #pragma unroll
    for (int j = 0; j < 8; j++) b[j] = *reinterpret_cast<const bf16x8*>(cb0 + j * 32);

    // chars + input-term prefetch for (t=0, tile 0)
    int ch[4];
    #pragma unroll
    for (int j = 0; j < 4; j++) ch[j] = char_lds[0][l4 * 4 + j];
    f32x4 inN;
    #pragma unroll
    for (int j = 0; j < 4; j++)
        inN[j] = wih_tb[(size_t)ch[j] * N_G + (wid * 64 + l15)];

    int rd = 0;
    for (int t = 0; t < N_C; t++) {
        const unsigned short* ha = &h_lds[rd][l15][l4 * 8];   // A base (old h)
        f32x4 gacc[4];
        int chn[4];

        #pragma unroll
        for (int tile = 0; tile < 16; tile++) {
            const int cg = tile >> 2, q = tile & 3;
            const int ncol = q * N_H + wid * 64 + cg * 16 + l15;
            const unsigned short* cb = whh_bf + (size_t)ncol * N_H + l4 * 8;

            const unsigned short* nb;
            int ncol_n = 0;
            if (tile == 15) {
                nb = wo_bf + (size_t)(wid * 16 + l15) * N_H + l4 * 8;
            } else {
                const int nt = tile + 1;
                ncol_n = (nt & 3) * N_H + wid * 64 + (nt >> 2) * 16 + l15;
                nb = whh_bf + (size_t)ncol_n * N_H + l4 * 8;
            }

            f32x4 acc = inN;   // input one-hot term + bias (prefetched)

            // prefetch input term for the NEXT tile
            if (tile < 15) {
                #pragma unroll
                for (int j = 0; j < 4; j++)
                    inN[j] = wih_tb[(size_t)ch[j] * N_G + ncol_n];
            } else {
                const int tn = (t + 1 < N_C) ? t + 1 : N_C - 1;
                #pragma unroll
                for (int j = 0; j < 4; j++) chn[j] = char_lds[tn][l4 * 4 + j];
                #pragma unroll
                for (int j = 0; j < 4; j++)
                    inN[j] = wih_tb[(size_t)chn[j] * N_G + (wid * 64 + l15)];
            }

            // half A: consume frag kk, refill slot kk with current tile frag kk+8
            #pragma unroll
            for (int kk = 0; kk < 8; kk++) {
                bf16x8 afr = *reinterpret_cast<const bf16x8*>(ha + kk * 32);
                acc = __builtin_amdgcn_mfma_f32_16x16x32_bf16(afr, b[kk], acc, 0, 0, 0);
                b[kk] = *reinterpret_cast<const bf16x8*>(cb + (kk + 8) * 32);
            }
            // half B: consume frag kk+8, refill slot kk with NEXT tile frag kk
            #pragma unroll
            for (int kk = 0; kk < 8; kk++) {
                bf16x8 afr = *reinterpret_cast<const bf16x8*>(ha + (kk + 8) * 32);
                acc = __builtin_amdgcn_mfma_f32_16x16x32_bf16(afr, b[kk], acc, 0, 0, 0);
                b[kk] = *reinterpret_cast<const bf16x8*>(nb + kk * 32);
            }

            gacc[q] = acc;

            if (q == 3) {
                // LSTM elementwise — i,f,g,o resident in this wave's registers
                f32x4 hfrag;
                #pragma unroll
                for (int j = 0; j < 4; j++) {
                    const float iv = gacc[0][j], fv = gacc[1][j], gv = gacc[2][j], ov = gacc[3][j];
                    const float si = 1.f / (1.f + __expf(-iv));
                    const float sf = 1.f / (1.f + __expf(-fv));
                    const float so = 1.f / (1.f + __expf(-ov));
                    const float tg = 1.f - 2.f / (__expf(2.f * gv) + 1.f);
                    const float cn = sf * cst[cg][j] + si * tg;
                    cst[cg][j] = cn;
                    const float th = 1.f - 2.f / (__expf(2.f * cn) + 1.f);
                    hfrag[j] = so * th;
                }
                const int hc = wid * 64 + cg * 16 + l15;
                #pragma unroll
                for (int j = 0; j < 4; j++)
                    h_lds[rd ^ 1][l4 * 4 + j][hc] = f2bf(hfrag[j]);
            }
        }
        #pragma unroll
        for (int j = 0; j < 4; j++) ch[j] = chn[j];

        __syncthreads();   // all waves done reading old h / writing new h
        rd ^= 1;           // new h becomes current

        // logits = h_new @ Wo.T + bo ; ring holds Wo frags 0..7.
        // half A refills Wo frags 8..15; half B refills next step's tile-0.
        const unsigned short* hl = &h_lds[rd][l15][l4 * 8];
        const unsigned short* wb = wo_bf + (size_t)(wid * 16 + l15) * N_H + l4 * 8;
        f32x4 lacc = {bo_v, bo_v, bo_v, bo_v};
        #pragma unroll
        for (int kk = 0; kk < 8; kk++) {
            bf16x8 afr = *reinterpret_cast<const bf16x8*>(hl + kk * 32);
            lacc = __builtin_amdgcn_mfma_f32_16x16x32_bf16(afr, b[kk], lacc, 0, 0, 0);
            b[kk] = *reinterpret_cast<const bf16x8*>(wb + (kk + 8) * 32);
        }
        #pragma unroll
        for (int kk = 0; kk < 8; kk++) {
            bf16x8 afr = *reinterpret_cast<const bf16x8*>(hl + (kk + 8) * 32);
            lacc = __builtin_amdgcn_mfma_f32_16x16x32_bf16(afr, b[kk], lacc, 0, 0, 0);
            b[kk] = *reinterpret_cast<const bf16x8*>(cb0 + kk * 32);
        }

        #pragma unroll
        for (int j = 0; j < 4; j++)
            logits_lds[l4 * 4 + j][wid * 16 + l15] = lacc[j];
        __syncthreads();

        // coalesced non-temporal store: 16 rows x 512B contiguous segments
        {
            const int row = tid >> 5, seg = tid & 31;
            f32x4 v = *reinterpret_cast<const f32x4*>(&logits_lds[row][seg * 4]);
            f32x4* dst = reinterpret_cast<f32x4*>(
                out + ((size_t)(r0 + row) * N_C + t) * N_A + seg * 4);
            __builtin_nontemporal_store(v, dst);
        }
    }
}

extern "C" void kernel_launch(void* const* d_in, const int* in_sizes, int n_in,
                              void* d_out, int out_size, void* d_ws, size_t ws_size,
                              hipStream_t stream) {
    const float* qr  = (const float*)d_in[0];
    const int*   tch = (const int*)d_in[1];
    const float* Wp  = (const float*)d_in[2];
    const float* bp  = (const float*)d_in[3];
    const float* Wih = (const float*)d_in[4];
    const float* Whh = (const float*)d_in[5];
    const float* bih = (const float*)d_in[6];
    const float* bhh = (const float*)d_in[7];
    const float* Wo  = (const float*)d_in[8];
    const float* bo  = (const float*)d_in[9];
    float* out = (float*)d_out;

    char* ws = (char*)d_ws;
    unsigned short* whh_bf = (unsigned short*)(ws + WS_WHH);
    unsigned short* wo_bf  = (unsigned short*)(ws + WS_WO);
    unsigned short* wp_bf  = (unsigned short*)(ws + WS_WP);
    float* wih_tb          = (float*)(ws + WS_WIHT);

    prep_kernel<<<1024, 256, 0, stream>>>(Whh, Wo, Wp, bih, bhh, Wih,
                                          whh_bf, wo_bf, wp_bf, wih_tb);
    lstm_kernel<<<N_BW / 16, 512, 0, stream>>>(qr, tch, bp, whh_bf, wo_bf, wp_bf,
                                               wih_tb, bo, out);
}